// Round 6
// baseline (30125.815 us; speedup 1.0000x reference)
//
#include <hip/hip_runtime.h>

// ULSTM layer: S=1024, B=32, IN=1024, H=1024
//  R8 = R5 protocol (fence-free coherent exchange + per-thread vmcnt drain
//  before flag release) with 4x FATTER BLOCKS: GBLK 64->16, 1024 thr/block,
//  each block owns 64 hidden cols. Rationale: R5's phase cost is dominated
//  by the h/v broadcast — every block reads the full 64KB state uncached
//  (sc0 sc1) from the IF$, so traffic scales with block count (64 x 64KB =
//  4MB/phase). 16 blocks cut that 4x; per-wave MFMA work is unchanged.
//  R7's tag-in-data poll was a regression (5e8 LDS bank conflicts from u16
//  scatter + RTT-quantized poll rounds) — reverted.

typedef unsigned short u16;
typedef __attribute__((ext_vector_type(4))) float f32x4;
typedef __attribute__((ext_vector_type(8))) short s16x8;     // 8 bf16 (MFMA A/B frag)
typedef __attribute__((ext_vector_type(8))) unsigned short u16x8;

#define SEQ   1024
#define BATCH 32
#define HDIM  1024
#define GBLK  16          // persistent blocks; each owns 64 hidden cols

__device__ __forceinline__ u16 f2bf(float f) {
    unsigned u = __builtin_bit_cast(unsigned, f);
    return (u16)((u + 0x7FFFu + ((u >> 16) & 1u)) >> 16);   // RNE
}
__device__ __forceinline__ float bf2f(u16 h) {
    return __builtin_bit_cast(float, (unsigned)h << 16);
}

// ---- coherent (L1+L2-bypassing) accessors for cross-block state -------------
__device__ __forceinline__ u16x8 gload_cc(const u16* p) {
    u16x8 v;
    asm volatile("global_load_dwordx4 %0, %1, off sc0 sc1" : "=&v"(v) : "v"(p));
    return v;
}
__device__ __forceinline__ void vmwait0() {
    asm volatile("s_waitcnt vmcnt(0)" ::: "memory");
    __builtin_amdgcn_sched_barrier(0);       // rule #18: pin uses after the wait
}
__device__ __forceinline__ void gstore_cc(u16* p, u16 d) {
    unsigned x = d;
    asm volatile("global_store_short %0, %1, off sc0 sc1" :: "v"(p), "v"(x) : "memory");
}

// ---------------------------------------------------------------- prep kernels
__global__ void prep_w0(const float* __restrict__ W, const float* __restrict__ b_ux,
                        const float* __restrict__ b_h, const float* __restrict__ b_um,
                        u16* __restrict__ W0p, float* __restrict__ biasp) {
    int p = blockIdx.x;                       // 5120
    int g = p / 80, r = p % 80, gate = r >> 4, j = r & 15;
    int n = 16 * g + j;
    int c = (gate < 4) ? gate * 1024 + n : 4096 + n;
    for (int k = threadIdx.x; k < 1024; k += 256)
        W0p[(long)p * 1024 + k] = f2bf(W[(long)k * 5120 + c]);
    if (threadIdx.x == 0)
        biasp[p] = b_ux[c] + ((gate < 4) ? b_h[gate * 1024 + n] : b_um[n]);
}

__global__ void prep_w1(const float* __restrict__ W, u16* __restrict__ W1p) {
    int qq = blockIdx.x;                      // 4096
    int g = qq >> 6, r = qq & 63, gate = r >> 4, j = r & 15;
    int n = 16 * g + j;
    int c = gate * 1024 + n;
    for (int k = threadIdx.x; k < 1024; k += 256)
        W1p[(long)qq * 1024 + k] = f2bf(W[(long)k * 4096 + c]);
}

__global__ void prep_w2(const float* __restrict__ W, u16* __restrict__ W2p) {
    int n = blockIdx.x;                       // 1024
    for (int k = threadIdx.x; k < 1024; k += 256)
        W2p[(long)n * 1024 + k] = f2bf(W[(long)k * 1024 + n]);
}

// ---------------------------------------------------------- input projection
__global__ void __launch_bounds__(256) gemm_in(const float* __restrict__ X,
                                               const u16* __restrict__ W0p,
                                               const float* __restrict__ biasp,
                                               u16* __restrict__ Yp) {
    __shared__ u16 As[128 * 40];
    __shared__ u16 Bs[64 * 40];
    const int tid = threadIdx.x, lane = tid & 63, w = tid >> 6;
    const int m = lane & 15, q = lane >> 4;
    const int m0 = blockIdx.y * 128, n0 = blockIdx.x * 64;

    f32x4 acc[2][4];
#pragma unroll
    for (int a = 0; a < 2; ++a)
#pragma unroll
        for (int b = 0; b < 4; ++b) acc[a][b] = (f32x4){0.f, 0.f, 0.f, 0.f};

    const int ar = tid >> 1, as = (tid & 1) * 16;
    const int br = tid >> 2, bs = (tid & 3) * 8;

    for (int k0 = 0; k0 < 1024; k0 += 32) {
        const float* xp = X + (long)(m0 + ar) * 1024 + k0 + as;
        float4 x0 = *(const float4*)(xp);
        float4 x1 = *(const float4*)(xp + 4);
        float4 x2 = *(const float4*)(xp + 8);
        float4 x3 = *(const float4*)(xp + 12);
        u16x8 pa, pb;
        pa[0]=f2bf(x0.x); pa[1]=f2bf(x0.y); pa[2]=f2bf(x0.z); pa[3]=f2bf(x0.w);
        pa[4]=f2bf(x1.x); pa[5]=f2bf(x1.y); pa[6]=f2bf(x1.z); pa[7]=f2bf(x1.w);
        pb[0]=f2bf(x2.x); pb[1]=f2bf(x2.y); pb[2]=f2bf(x2.z); pb[3]=f2bf(x2.w);
        pb[4]=f2bf(x3.x); pb[5]=f2bf(x3.y); pb[6]=f2bf(x3.z); pb[7]=f2bf(x3.w);
        u16x8 bv = *(const u16x8*)(W0p + (long)(n0 + br) * 1024 + k0 + bs);

        *(u16x8*)&As[ar * 40 + as]     = pa;
        *(u16x8*)&As[ar * 40 + as + 8] = pb;
        *(u16x8*)&Bs[br * 40 + bs]     = bv;
        __syncthreads();

        s16x8 a0 = *(const s16x8*)&As[(w * 32 + m) * 40 + q * 8];
        s16x8 a1 = *(const s16x8*)&As[(w * 32 + 16 + m) * 40 + q * 8];
#pragma unroll
        for (int nt = 0; nt < 4; ++nt) {
            s16x8 b = *(const s16x8*)&Bs[(nt * 16 + m) * 40 + q * 8];
            acc[0][nt] = __builtin_amdgcn_mfma_f32_16x16x32_bf16(a0, b, acc[0][nt], 0, 0, 0);
            acc[1][nt] = __builtin_amdgcn_mfma_f32_16x16x32_bf16(a1, b, acc[1][nt], 0, 0, 0);
        }
        __syncthreads();
    }
#pragma unroll
    for (int mt = 0; mt < 2; ++mt)
#pragma unroll
        for (int nt = 0; nt < 4; ++nt) {
            int p = n0 + nt * 16 + m;
            int gg = p / 80, rr = p - gg * 80;
            float bias = biasp[p];
#pragma unroll
            for (int r = 0; r < 4; ++r) {
                int row = m0 + w * 32 + mt * 16 + q * 4 + r;
                int s = row >> 5, b = row & 31;
                Yp[(((long)gg * 1024 + s) * 32 + b) * 80 + rr] = f2bf(acc[mt][nt][r] + bias);
            }
        }
}

// -------------------------------------------------------------- grid barrier
// 16 flags, 128B apart. EVERY thread drains its own vmcnt first (per-wave!)
// so all coherent publishes are at the IF$ before wave 0 releases the flag.
// No acquire fence on exit: consumers use sc0 sc1 reads only -> weights stay
// L2-resident across all timesteps.
__device__ __forceinline__ void gridbar(unsigned* flags, unsigned phase, int g) {
    asm volatile("s_waitcnt vmcnt(0)" ::: "memory");   // per-wave store drain
    __syncthreads();
    if (threadIdx.x < 64) {
        unsigned v;
        if (threadIdx.x == 0)
            __hip_atomic_store(&flags[g * 32], phase, __ATOMIC_RELEASE,
                               __HIP_MEMORY_SCOPE_AGENT);
        for (;;) {
            v = (threadIdx.x < GBLK)
                    ? __hip_atomic_load(&flags[threadIdx.x * 32], __ATOMIC_RELAXED,
                                        __HIP_MEMORY_SCOPE_AGENT)
                    : phase;
            if (__ballot(v >= phase) == ~0ull) break;
            __builtin_amdgcn_s_sleep(1);
        }
    }
    __syncthreads();
}

// ------------------------------------------------------------- recurrence
// Block g owns cols [64g, 64g+64). 16 waves: gemm1 wave w -> gate gw=w>>2,
// col-block cb=w&3 (16 cols). gemm2 waves w<8: row-half rh=w&1, col-block
// cb2=w>>1. stage stride 1028 keeps ds_read_b128 at free 2-way aliasing.
__global__ void __launch_bounds__(1024, 1) ulstm_rec(const u16* __restrict__ W1p,
                                                     const u16* __restrict__ W2p,
                                                     const u16* __restrict__ Yp,
                                                     u16* h_buf, u16* v_buf,
                                                     float* __restrict__ out,
                                                     unsigned* flags) {
    __shared__ u16 stage[32 * 1028];        // 65,792 B: h (A) / v (B)
    __shared__ u16 ys[2][4][2560];          // 40,960 B: Y slices, 4 groups
    __shared__ float gl[4][32][66];         // 33,792 B: i,o,(z unused),f
    __shared__ float c_l[32][66], ct_l[32][66];   // 16,896 B

    const int g = blockIdx.x, tid = threadIdx.x, lane = tid & 63, w = tid >> 6;
    const int m = lane & 15, q = lane >> 4;
    const int nb = g * 64;                  // first owned hidden col

    for (int i = tid; i < 32 * 66; i += 1024) {
        ((float*)c_l)[i] = 0.f; ((float*)ct_l)[i] = 0.f;
    }
    for (int i = tid; i < 2048; i += 1024) {         // publish h_0 = 0
        int row = i >> 6, col = i & 63;
        gstore_cc(&h_buf[row * 1024 + nb + col], (u16)0);
    }
    {   // Y slice for t=0
        for (int i = tid; i < 1280; i += 1024) {
            int cb = i / 320, wi = i - cb * 320;
            const u16x8* src = (const u16x8*)(Yp + (long)(4 * g + cb) * 1024 * 2560);
            *(u16x8*)&ys[0][cb][wi * 8] = __builtin_nontemporal_load(&src[wi]);
        }
    }
    unsigned phase = 1;
    gridbar(flags, phase, g);               // drains h_0 publishes, syncs grid

    for (int t = 0; t < SEQ; ++t) {
        const u16 (*ysb)[2560] = ys[t & 1];

        // ---- phase A: issue Y(t+1)->regs and h->regs together (latencies
        // overlap: Y is HBM/L3, h is IF$-coherent), then drain, stage h.
        u16x8 yreg[2];
        int yi0 = tid, yi1 = tid + 1024;
        if (t + 1 < SEQ) {
            {
                int cb = yi0 / 320, wi = yi0 - cb * 320;
                const u16x8* src = (const u16x8*)(Yp + ((long)(4 * g + cb) * 1024 + t + 1) * 2560);
                yreg[0] = __builtin_nontemporal_load(&src[wi]);
            }
            if (yi1 < 1280) {
                int cb = yi1 / 320, wi = yi1 - cb * 320;
                const u16x8* src = (const u16x8*)(Yp + ((long)(4 * g + cb) * 1024 + t + 1) * 2560);
                yreg[1] = __builtin_nontemporal_load(&src[wi]);
            }
        }
        u16x8 hreg[4];
#pragma unroll
        for (int j = 0; j < 4; ++j) {
            int idx = tid + j * 1024;
            hreg[j] = gload_cc(&h_buf[(idx >> 7) * 1024 + (idx & 127) * 8]);
        }
        vmwait0();
#pragma unroll
        for (int j = 0; j < 4; ++j) {
            int idx = tid + j * 1024;
            *(u16x8*)&stage[(idx >> 7) * 1028 + (idx & 127) * 8] = hreg[j];
        }
        __syncthreads();                              // sync#1: h staged

        // ---- gemm1: all 16 waves; wave w: gate gw, col-block cb
        const int gw = w >> 2, cb = w & 3;
        f32x4 acc0 = (f32x4){0.f,0.f,0.f,0.f}, acc1 = (f32x4){0.f,0.f,0.f,0.f};
        {
            const int brow = (4 * g + cb) * 64 + gw * 16 + m;
            const u16* wp = W1p + (long)brow * 1024;
#pragma unroll 8
            for (int kc = 0; kc < 32; ++kc) {
                int k0 = kc * 32 + q * 8;
                s16x8 a0 = *(const s16x8*)&stage[m * 1028 + k0];
                s16x8 a1 = *(const s16x8*)&stage[(16 + m) * 1028 + k0];
                s16x8 b  = *(const s16x8*)&wp[k0];
                acc0 = __builtin_amdgcn_mfma_f32_16x16x32_bf16(a0, b, acc0, 0, 0, 0);
                acc1 = __builtin_amdgcn_mfma_f32_16x16x32_bf16(a1, b, acc1, 0, 0, 0);
            }
        }
        {
            const int col = cb * 16 + m;
#pragma unroll
            for (int r = 0; r < 4; ++r) {
                int row0 = q * 4 + r, row1 = row0 + 16;
                float p0 = acc0[r] + bf2f(ysb[cb][row0 * 80 + gw * 16 + m]);
                float p1 = acc1[r] + bf2f(ysb[cb][row1 * 80 + gw * 16 + m]);
                float g0 = 1.f / (1.f + __expf(-p0));
                float g1 = 1.f / (1.f + __expf(-p1));
                if (gw == 2) {   // z-gate: publish v = sigmoid(z)*tanh(c_prev)
                    gstore_cc(&v_buf[row0 * 1024 + nb + col], f2bf(g0 * ct_l[row0][col]));
                    gstore_cc(&v_buf[row1 * 1024 + nb + col], f2bf(g1 * ct_l[row1][col]));
                } else {
                    gl[gw][row0][col] = g0;
                    gl[gw][row1][col] = g1;
                }
            }
        }
        gridbar(flags, ++phase, g);                   // v published grid-wide

        // ---- phase B: park Y(t+1) regs into LDS (no sync needed before
        // next-step read: sync#3/#4/#1 intervene), then stage v.
        if (t + 1 < SEQ) {
            {
                int cb2 = yi0 / 320, wi = yi0 - cb2 * 320;
                *(u16x8*)&ys[(t + 1) & 1][cb2][wi * 8] = yreg[0];
            }
            if (yi1 < 1280) {
                int cb2 = yi1 / 320, wi = yi1 - cb2 * 320;
                *(u16x8*)&ys[(t + 1) & 1][cb2][wi * 8] = yreg[1];
            }
        }
        u16x8 vreg[4];
#pragma unroll
        for (int j = 0; j < 4; ++j) {
            int idx = tid + j * 1024;
            vreg[j] = gload_cc(&v_buf[(idx >> 7) * 1024 + (idx & 127) * 8]);
        }
        vmwait0();
#pragma unroll
        for (int j = 0; j < 4; ++j) {
            int idx = tid + j * 1024;
            *(u16x8*)&stage[(idx >> 7) * 1028 + (idx & 127) * 8] = vreg[j];
        }
        __syncthreads();                              // sync#3: v staged

        // ---- gemm2 + state update (waves 0..7: rh = w&1, cb2 = w>>1)
        if (w < 8) {
            const int rh = w & 1, cb2 = w >> 1;
            const int col = cb2 * 16 + m;
            f32x4 acc = (f32x4){0.f,0.f,0.f,0.f};
            const u16* wp = W2p + (long)(nb + col) * 1024;
#pragma unroll 8
            for (int kc = 0; kc < 32; ++kc) {
                int k0 = kc * 32 + q * 8;
                s16x8 a = *(const s16x8*)&stage[(rh * 16 + m) * 1028 + k0];
                s16x8 b = *(const s16x8*)&wp[k0];
                acc = __builtin_amdgcn_mfma_f32_16x16x32_bf16(a, b, acc, 0, 0, 0);
            }
#pragma unroll
            for (int r = 0; r < 4; ++r) {
                int row = rh * 16 + q * 4 + r;
                float up = acc[r] + bf2f(ysb[cb2][row * 80 + 64 + m]);
                float eu = __expf(2.f * up);
                float u = 1.f - 2.f / (eu + 1.f);           // tanh
                float iv = gl[0][row][col], ov = gl[1][row][col], fv = gl[3][row][col];
                float cv = c_l[row][col];
                float cn = iv * u + fv * cv;
                float ec = __expf(2.f * cn);
                float ctn = 1.f - 2.f / (ec + 1.f);
                float hn = ov * ctn;
                c_l[row][col] = cn;
                ct_l[row][col] = ctn;
                gstore_cc(&h_buf[row * 1024 + nb + col], f2bf(hn));
                __builtin_nontemporal_store(hn, &out[(long)(t * 32 + row) * 1024 + nb + col]);
                if (t == SEQ - 1) {
                    out[33554432l + row * 1024 + nb + col] = hn;          // h_n
                    out[33554432l + 32768 + row * 1024 + nb + col] = cn;  // c_n
                }
            }
        }
        gridbar(flags, ++phase, g);                   // h published grid-wide
    }
}

// ---------------------------------------------------------------------- host
extern "C" void kernel_launch(void* const* d_in, const int* in_sizes, int n_in,
                              void* d_out, int out_size, void* d_ws, size_t ws_size,
                              hipStream_t stream) {
    (void)in_sizes; (void)n_in; (void)out_size; (void)ws_size;
    const float* X  = (const float*)d_in[0];
    const float* W0 = (const float*)d_in[1];
    const float* b0 = (const float*)d_in[2];
    const float* W1 = (const float*)d_in[3];
    const float* b1 = (const float*)d_in[4];
    const float* W2 = (const float*)d_in[5];
    const float* b2 = (const float*)d_in[6];
    float* out = (float*)d_out;
    char* ws = (char*)d_ws;

    u16*   Yp    = (u16*)(ws);                      // 335,544,320 B
    u16*   W0p   = (u16*)(ws + 335544320l);         // 10,485,760
    u16*   W1p   = (u16*)(ws + 346030080l);         // 8,388,608
    u16*   W2p   = (u16*)(ws + 354418688l);         // 2,097,152
    float* biasp = (float*)(ws + 356515840l);       // 20,480
    u16*   h_buf = (u16*)(ws + 356536320l);         // 65,536
    u16*   v_buf = (u16*)(ws + 356601856l);         // 65,536
    unsigned* flags = (unsigned*)(ws + 356667392l); // 8,192 (16 x 128B used)

    hipMemsetAsync(flags, 0, 8192, stream);
    prep_w0<<<5120, 256, 0, stream>>>(W0, b0, b1, b2, W0p, biasp);
    prep_w1<<<4096, 256, 0, stream>>>(W1, W1p);
    prep_w2<<<1024, 256, 0, stream>>>(W2, W2p);
    gemm_in<<<dim3(80, 256), 256, 0, stream>>>(X, W0p, biasp, Yp);

    void* args[] = { (void*)&W1p, (void*)&W2p, (void*)&Yp,
                     (void*)&h_buf, (void*)&v_buf, (void*)&out, (void*)&flags };
    hipLaunchCooperativeKernel(reinterpret_cast<void*>(ulstm_rec),
                               dim3(GBLK), dim3(1024), args, 0, stream);
}